// Round 7
// baseline (7301.815 us; speedup 1.0000x reference)
//
#include <hip/hip_runtime.h>

#define TSTEPS 2048
#define VDIM 128
#define FDIM 512

typedef __attribute__((ext_vector_type(8))) _Float16 half8;
typedef __attribute__((ext_vector_type(4))) _Float16 half4;
typedef __attribute__((ext_vector_type(4))) float floatx4;
typedef unsigned long long u64;

// ws layout (bytes):
//   [0,512K)        WH: f16 hi, frag order [chunk32][kk16][lane64][e8]
//   [512K,1M)       WL: f16 lo*4096, same order
//   [1M,1M+128K)    r parity-0: [g8][kk16][lane64][e8] f16 (16KB/group)
//   [1M+128K,+256K) r parity-1: same
#define WS_WH 0
#define WS_WL (512u * 1024u)
#define WS_R  (1024u * 1024u)

// Pre-swizzle W (fp32 row-major [j][k]) into A-frag order, hi + lo*4096.
// A-frag (16x16x32 f16): lane l holds row (l&15), k = kk*32 + (l>>4)*8 + e.
__global__ __launch_bounds__(256) void rnn_prep(const float* __restrict__ W,
                                                _Float16* __restrict__ WH,
                                                _Float16* __restrict__ WL) {
  int tid = blockIdx.x * 256 + threadIdx.x;   // 32 chunks * 16 kk * 64 lanes
  int c  = tid >> 10;
  int kk = (tid >> 6) & 15;
  int l  = tid & 63;
  int j  = 16 * c + (l & 15);
  int k0 = kk * 32 + (l >> 4) * 8;
  const float* src = W + j * FDIM + k0;
  half8 vh, vl;
#pragma unroll
  for (int e = 0; e < 8; ++e) {
    float w = src[e];
    _Float16 h = (_Float16)w;
    vh[e] = h;
    vl[e] = (_Float16)((w - (float)h) * 4096.0f);
  }
  *(half8*)(WH + (size_t)tid * 8) = vh;
  *(half8*)(WL + (size_t)tid * 8) = vl;
}

__device__ __forceinline__ u64 AL(const char* p) {
  return __hip_atomic_load((const u64*)p, __ATOMIC_RELAXED,
                           __HIP_MEMORY_SCOPE_AGENT);
}

// 32 WGs = 8 row-groups (g) x 4 slices (s), 512 thr = 8 waves.
// Tag-in-data exchange (proven R4): r in B-frag order, step-tag
// tau(t)=(t>>1)&1 in every f16 LSB.  R7: NO __syncthreads in the loop.
// Wave w global-polls its 2 chunks (R4 volume), relays them into LDS with
// tags intact; the kk-loop polls LDS per-chunk just-in-time (period ~60cy),
// overlapping sibling-detection skew with MFMA on available chunks.
// LDS double-buffer WAR guarded by per-parity consumption counter gcnt.
__global__ void __launch_bounds__(512, 1)
rnn_main(const float* __restrict__ X, const float* __restrict__ bvec,
         const _Float16* __restrict__ WH, const _Float16* __restrict__ WL,
         _Float16* __restrict__ rbase, float* __restrict__ out) {
  __shared__ _Float16 lds[2][8192];           // 16KB per step-parity
  __shared__ unsigned gcnt[2];                // per-parity consume counters
  const int g  = blockIdx.x & 7;
  const int s  = blockIdx.x >> 3;
  const int w  = threadIdx.x >> 6;
  const int l  = threadIdx.x & 63;
  const int lr = l & 15;                      // D col = group-local state row
  const int lg = l >> 4;
  const int c  = 4 * w + s;                   // W chunk = feats [16c,16c+16)
  const int jb = 16 * c + lg * 4;             // this lane's 4 features

  // persistent W fragments (hi + lo): 128 regs, pinned
  half8 wh[16], wl[16];
#pragma unroll
  for (int kk = 0; kk < 16; ++kk) {
    wh[kk] = ((const half8*)WH)[(c * 16 + kk) * 64 + l];
    wl[kk] = ((const half8*)WL)[(c * 16 + kk) * 64 + l];
    asm volatile("" : "+v"(wh[kk]), "+v"(wl[kk]));
  }

  const floatx4 bv = *(const floatx4*)(bvec + jb);
  const bool vis = (16 * c < 128);
  const bool diagHere = (c == g);
  const u64 TAGM = 0x0001000100010001ULL;

  // global poll region: wave w owns chunks 2w (bytes [pc,pc+16)/lane), 2w+1
  const int pc = (2 * w) * 1024 + l * 16;
  // produced half4 frag offset (halves): kk*512 + (sub*16+lr)*8 + (jb&7)
  const int so = ((jb >> 5) << 9) + ((((jb >> 3) & 3) << 4) + lr) * 8 + (jb & 7);

  // init: lds[0] = r(0) = 0 with tag 0 (valid); lds[1] = tag-1 bytes (invalid
  // for want(t=1)=0); counters zero.  Only barrier in the kernel.
  {
    ulonglong2 z0; z0.x = 0; z0.y = 0;
    u64 o = 0x0101010101010101ULL;
    ulonglong2 z1; z1.x = o; z1.y = o;
    ((ulonglong2*)lds[0])[threadIdx.x] = z0;
    ((ulonglong2*)lds[0])[512 + threadIdx.x] = z0;
    ((ulonglong2*)lds[1])[threadIdx.x] = z1;
    ((ulonglong2*)lds[1])[512 + threadIdx.x] = z1;
    if (threadIdx.x == 0) { gcnt[0] = 0; gcnt[1] = 0; }
  }
  __syncthreads();

  int budget = 4000000;

  for (int t = 0; t < TSTEPS; ++t) {
    const int p = t & 1;
    floatx4 xv = {0.f, 0.f, 0.f, 0.f};
    if (vis) xv = *(const floatx4*)(X + t * VDIM + jb);
    asm volatile("" : "+v"(xv));              // issue X before the polls

    // ---- global poll of own 2 chunks (R4-style, simple re-issue)
    const char* rb = (const char*)rbase + (size_t)p * (128 * 1024)
                   + (size_t)g * 16384;
    const u64 want = (u64)((t >> 1) & 1) * TAGM;
    u64 v0, v1, v2, v3;
    for (;;) {
      v0 = AL(rb + pc);        v1 = AL(rb + pc + 8);
      v2 = AL(rb + pc + 1024); v3 = AL(rb + pc + 1032);
      int ok = ((v0 & TAGM) == want) & ((v1 & TAGM) == want) &
               ((v2 & TAGM) == want) & ((v3 & TAGM) == want);
      if (__all(ok)) break;
      if (--budget < 0) break;
    }

    // ---- WAR guard: step t-2 readers of lds[p] must be done (8 waves each
    // add 1 per step => need gcnt[p] >= 8*(t>>1)).  Normally zero wait.
    {
      const unsigned thr = 8u * (unsigned)(t >> 1);
      while (__hip_atomic_load(&gcnt[p], __ATOMIC_RELAXED,
                               __HIP_MEMORY_SCOPE_WORKGROUP) < thr) {
        if (--budget < 0) break;
      }
    }

    // ---- relay own chunks into LDS (tags intact)
    char* lp = (char*)lds[p];
    { ulonglong2 a; a.x = v0; a.y = v1; *(ulonglong2*)(lp + pc) = a; }
    { ulonglong2 a; a.x = v2; a.y = v3; *(ulonglong2*)(lp + pc + 1024) = a; }

    // ---- kk-loop: poll each chunk in LDS just-in-time, then 2 MFMAs.
    // 4 accumulator chains (even/odd kk x hi/lo) to halve dep latency.
    floatx4 aH0 = {0.f,0.f,0.f,0.f}, aH1 = {0.f,0.f,0.f,0.f};
    floatx4 aL0 = {0.f,0.f,0.f,0.f}, aL1 = {0.f,0.f,0.f,0.f};
#pragma unroll
    for (int kk = 0; kk < 16; ++kk) {
      const volatile u64* q = (const volatile u64*)(lp + kk * 1024 + l * 16);
      u64 q0, q1;
      for (;;) {
        q0 = q[0]; q1 = q[1];
        if (__all(((q0 & TAGM) == want) & ((q1 & TAGM) == want))) break;
        if (--budget < 0) break;
      }
      union { u64 u[2]; half8 h; } bb; bb.u[0] = q0; bb.u[1] = q1;
      if (kk & 1) {
        aH1 = __builtin_amdgcn_mfma_f32_16x16x32_f16(wh[kk], bb.h, aH1, 0, 0, 0);
        aL1 = __builtin_amdgcn_mfma_f32_16x16x32_f16(wl[kk], bb.h, aL1, 0, 0, 0);
      } else {
        aH0 = __builtin_amdgcn_mfma_f32_16x16x32_f16(wh[kk], bb.h, aH0, 0, 0, 0);
        aL0 = __builtin_amdgcn_mfma_f32_16x16x32_f16(wl[kk], bb.h, aL0, 0, 0, 0);
      }
    }

    // ---- mark lds[p] consumed (after all ds reads of this wave)
    asm volatile("" ::: "memory");
    if (l == 0)
      __hip_atomic_fetch_add(&gcnt[p], 1u, __ATOMIC_RELAXED,
                             __HIP_MEMORY_SCOPE_WORKGROUP);

    // ---- epilogue: combine, blend, tanh, tag, publish r(t+1)
    const bool last = (t == TSTEPS - 1);
    union { half4 h; u64 u; } pk; pk.u = 0;
#pragma unroll
    for (int v = 0; v < 4; ++v) {
      float u = (aH0[v] + aH1[v]) + (aL0[v] + aL1[v]) * 2.44140625e-4f + bv[v];
      const bool isdiag = diagHere && (lg * 4 + v == lr);
      if (vis && !isdiag) u = 0.5f * u + 0.5f * xv[v];
      if (last) {
        if (isdiag) out[16 * g + lr] = u;     // diag of U, pre-tanh
      } else {
        float au = fabsf(u);
        float e2 = __expf(-2.0f * au);
        float th = __fdividef(1.0f - e2, 1.0f + e2);
        pk.h[v] = (_Float16)copysignf(th, u);
      }
    }

    if (!last) {
      const u64 ntag = (u64)(((t + 1) >> 1) & 1) * TAGM;
      u64 val = (pk.u & ~TAGM) | ntag;
      char* wbuf = (char*)rbase + (size_t)((t + 1) & 1) * (128 * 1024)
                 + (size_t)g * 16384;
      __hip_atomic_store((u64*)(wbuf + so * 2), val, __ATOMIC_RELAXED,
                         __HIP_MEMORY_SCOPE_AGENT);
    }
  }
}

extern "C" void kernel_launch(void* const* d_in, const int* in_sizes, int n_in,
                              void* d_out, int out_size, void* d_ws, size_t ws_size,
                              hipStream_t stream) {
  const float* X = (const float*)d_in[0];
  const float* W = (const float*)d_in[1];
  const float* b = (const float*)d_in[2];
  float* out = (float*)d_out;
  char* ws = (char*)d_ws;

  _Float16* WH = (_Float16*)(ws + WS_WH);
  _Float16* WL = (_Float16*)(ws + WS_WL);
  _Float16* rb = (_Float16*)(ws + WS_R);

  // parity-0 r: zeros (valid r(0), tag 0).  parity-1: 0x0101 (tag=1, invalid
  // for tau(1)=0).
  hipMemsetAsync(ws + WS_R, 0x00, 128 * 1024, stream);
  hipMemsetAsync(ws + WS_R + 128 * 1024, 0x01, 128 * 1024, stream);
  rnn_prep<<<128, 256, 0, stream>>>(W, WH, WL);
  rnn_main<<<32, 512, 0, stream>>>(X, b, WH, WL, rb, out);
}

// Round 9
// 3010.531 us; speedup vs baseline: 2.4254x; 2.4254x over previous
//
#include <hip/hip_runtime.h>

#define TSTEPS 2048
#define VDIM 128
#define FDIM 512

typedef __attribute__((ext_vector_type(8))) _Float16 half8;
typedef __attribute__((ext_vector_type(4))) _Float16 half4;
typedef __attribute__((ext_vector_type(4))) float floatx4;
typedef unsigned long long u64;
typedef __attribute__((ext_vector_type(2))) unsigned long long u64x2;

// ws layout (bytes):
//   [0,512K)        WH: f16, A-frag order [chunk32][kk16][lane64][e8]
//   [1M,1M+128K)    r parity-0: [g8][kk16][lane64][e8] f16 (16KB/group)
//   [1M+128K,+256K) r parity-1: same
#define WS_WH 0
#define WS_R  (1024u * 1024u)

// Pre-swizzle W (fp32 row-major [j][k]) into A-frag order, single f16.
// A-frag (16x16x32 f16): lane l holds row (l&15), k = kk*32 + (l>>4)*8 + e.
__global__ __launch_bounds__(256) void rnn_prep(const float* __restrict__ W,
                                                _Float16* __restrict__ WH) {
  int tid = blockIdx.x * 256 + threadIdx.x;   // 32 chunks * 16 kk * 64 lanes
  int c  = tid >> 10;
  int kk = (tid >> 6) & 15;
  int l  = tid & 63;
  int j  = 16 * c + (l & 15);
  int k0 = kk * 32 + (l >> 4) * 8;
  const float* src = W + j * FDIM + k0;
  half8 vh;
#pragma unroll
  for (int e = 0; e < 8; ++e) vh[e] = (_Float16)src[e];
  *(half8*)(WH + (size_t)tid * 8) = vh;
}

// 32 WGs = 8 row-groups (g) x 4 slices (s), 512 thr = 8 waves, wave owns
// chunk c = 4w+s (features [16c,16c+16)), W resident in 64 VGPRs.
// R4-proven protocol: tag-in-data (tau(t)=(t>>1)&1 in every f16 LSB), each
// wave polls only its own 2 exchange chunks via IC-coherent loads, shares
// through LDS, one barrier, MFMA from LDS, store r(t+1) write-through.
__global__ void __launch_bounds__(512, 2)
rnn_main(const float* __restrict__ X, const float* __restrict__ bvec,
         const _Float16* __restrict__ WH,
         _Float16* __restrict__ rbase, float* __restrict__ out) {
  __shared__ _Float16 lds[2][8192];           // 16KB per step-parity
  const int g  = blockIdx.x & 7;
  const int s  = blockIdx.x >> 3;
  const int w  = threadIdx.x >> 6;
  const int l  = threadIdx.x & 63;
  const int lr = l & 15;                      // D col = group-local state row
  const int lg = l >> 4;
  const int c  = 4 * w + s;                   // W chunk = feats [16c,16c+16)
  const int jb = 16 * c + lg * 4;             // this lane's 4 features

  // persistent W fragments: 16 x half8 = 64 VGPRs, pinned
  half8 wh[16];
#pragma unroll
  for (int kk = 0; kk < 16; ++kk) {
    wh[kk] = ((const half8*)WH)[(c * 16 + kk) * 64 + l];
    asm volatile("" : "+v"(wh[kk]));
  }

  const floatx4 bv = *(const floatx4*)(bvec + jb);
  const bool vis = (16 * c < 128);
  const bool diagHere = (c == g);
  const u64 TAGM = 0x0001000100010001ULL;

  // poll region: wave w owns exchange chunks 2w, 2w+1; 16B/lane each
  const int pc = (2 * w) * 1024 + l * 16;
  // produced half4 frag offset (halves): kk*512 + (sub*16+lr)*8 + (jb&7)
  const int so = ((jb >> 5) << 9) + ((((jb >> 3) & 3) << 4) + lr) * 8 + (jb & 7);

  int budget = 4000000;

  for (int t = 0; t < TSTEPS; ++t) {
    floatx4 xv = {0.f, 0.f, 0.f, 0.f};
    if (vis) xv = *(const floatx4*)(X + t * VDIM + jb);
    asm volatile("" : "+v"(xv));              // issue X before the polls

    // ---- poll own 2 chunks (IC-coherent 16B loads, R4 semantics)
    const char* rb = (const char*)rbase + (size_t)(t & 1) * (128 * 1024)
                   + (size_t)g * 16384;
    const u64 want = (u64)((t >> 1) & 1) * TAGM;
    u64 v0, v1, v2, v3;
    for (;;) {
      u64x2 A, B;
      asm volatile("global_load_dwordx4 %0, %2, off sc0 sc1\n\t"
                   "global_load_dwordx4 %1, %3, off sc0 sc1\n\t"
                   "s_waitcnt vmcnt(0)"
                   : "=&v"(A), "=&v"(B)
                   : "v"(rb + pc), "v"(rb + pc + 1024)
                   : "memory");
      v0 = A[0]; v1 = A[1]; v2 = B[0]; v3 = B[1];
      int ok = ((v0 & TAGM) == want) & ((v1 & TAGM) == want) &
               ((v2 & TAGM) == want) & ((v3 & TAGM) == want);
      if (__all(ok)) break;
      if (--budget < 0) break;
    }

    // ---- stage into LDS (linear frag order), share via one barrier
    char* lp = (char*)lds[t & 1];
    { ulonglong2 a; a.x = v0; a.y = v1; *(ulonglong2*)(lp + pc) = a; }
    { ulonglong2 a; a.x = v2; a.y = v3; *(ulonglong2*)(lp + pc + 1024) = a; }
    __syncthreads();

    // ---- MFMA: D[j][i] = sum_k W[j,k] r[i,k]; 2 acc chains (even/odd kk)
    floatx4 a0 = {0.f,0.f,0.f,0.f}, a1 = {0.f,0.f,0.f,0.f};
#pragma unroll
    for (int kk = 0; kk < 16; kk += 2) {
      half8 b0 = *(const half8*)(lp + kk * 1024 + l * 16);
      half8 b1 = *(const half8*)(lp + (kk + 1) * 1024 + l * 16);
      a0 = __builtin_amdgcn_mfma_f32_16x16x32_f16(wh[kk],     b0, a0, 0, 0, 0);
      a1 = __builtin_amdgcn_mfma_f32_16x16x32_f16(wh[kk + 1], b1, a1, 0, 0, 0);
    }

    // ---- epilogue: combine, blend, tanh, tag, publish r(t+1)
    const bool last = (t == TSTEPS - 1);
    union { half4 h; u64 u; } pk; pk.u = 0;
#pragma unroll
    for (int v = 0; v < 4; ++v) {
      float u = a0[v] + a1[v] + bv[v];
      const bool isdiag = diagHere && (lg * 4 + v == lr);
      if (vis && !isdiag) u = 0.5f * u + 0.5f * xv[v];
      if (last) {
        if (isdiag) out[16 * g + lr] = u;     // diag of U, pre-tanh
      } else {
        float au = fabsf(u);
        float e2 = __expf(-2.0f * au);
        float th = __fdividef(1.0f - e2, 1.0f + e2);
        pk.h[v] = (_Float16)copysignf(th, u);
      }
    }

    if (!last) {
      const u64 ntag = (u64)(((t + 1) >> 1) & 1) * TAGM;
      u64 val = (pk.u & ~TAGM) | ntag;
      char* wbuf = (char*)rbase + (size_t)((t + 1) & 1) * (128 * 1024)
                 + (size_t)g * 16384;
      __hip_atomic_store((u64*)(wbuf + so * 2), val, __ATOMIC_RELAXED,
                         __HIP_MEMORY_SCOPE_AGENT);
    }
  }
}

extern "C" void kernel_launch(void* const* d_in, const int* in_sizes, int n_in,
                              void* d_out, int out_size, void* d_ws, size_t ws_size,
                              hipStream_t stream) {
  const float* X = (const float*)d_in[0];
  const float* W = (const float*)d_in[1];
  const float* b = (const float*)d_in[2];
  float* out = (float*)d_out;
  char* ws = (char*)d_ws;

  _Float16* WH = (_Float16*)(ws + WS_WH);
  _Float16* rb = (_Float16*)(ws + WS_R);

  // parity-0 r: zeros (valid r(0), tag 0).  parity-1: 0x0101 (tag=1, invalid
  // for tau(1)=0).
  hipMemsetAsync(ws + WS_R, 0x00, 128 * 1024, stream);
  hipMemsetAsync(ws + WS_R + 128 * 1024, 0x01, 128 * 1024, stream);
  rnn_prep<<<128, 256, 0, stream>>>(W, WH);
  rnn_main<<<32, 512, 0, stream>>>(X, b, WH, rb, out);
}